// Round 8
// baseline (585.862 us; speedup 1.0000x reference)
//
#include <hip/hip_runtime.h>
#include <math.h>

#define B_ 32
#define N_ 8192
#define C_ 64
#define S_ 512
#define CIN 67
#define COUT 128

// ---------------------------------------------------------------------------
// DPP move helper: returns src shifted per CTRL; out-of-range lanes read 0.
// ---------------------------------------------------------------------------
template <int CTRL>
__device__ __forceinline__ unsigned dppmov(unsigned v) {
  return (unsigned)__builtin_amdgcn_update_dpp(0, (int)v, CTRL, 0xF, 0xF, true);
}

// one step of (hi,lo) lexicographic max against DPP-shifted neighbor
#define DPP_MAX_STEP(CTRL)                                                  \
  {                                                                         \
    unsigned shi = dppmov<CTRL>(hi);                                        \
    unsigned slo = dppmov<CTRL>(lo);                                        \
    bool gt = (shi > hi) || (shi == hi && slo > lo);                        \
    hi = gt ? shi : hi;                                                     \
    lo = gt ? slo : lo;                                                     \
  }

// ---------------------------------------------------------------------------
// Kernel 1: farthest point sampling. One block per batch, 256 threads
// (4 waves = 1 wave/SIMD), 32 points per thread; xyz mirrored in LDS (SoA).
// SCALAR __f*_rn distance math only — packed fp32 (v_pk_* / <2 x float>)
// diverged from numpy twice (r3, r7: identical absmax 2.33) and is banned.
// Changes vs r4 (both semantics-preserving):
//  * amdgpu_waves_per_eu(1,1): max occupancy = 1 wave/EU -> allocator gets
//    the full 512-VGPR budget, so the 128 state regs (px/py/pz/dist) can
//    stay resident instead of being re-read from LDS every step (the VGPR=132
//    plateau of r4-r6).
//  * tree argmax: in-loop value-only fmaxf (all dist >= +0 -> associative,
//    bestv bit-identical), then lowest matching index via min-tree over
//    (dist[j]==bestv ? j : BIG) — first occurrence, same as serial '>' and
//    numpy argmax — replacing the 32-deep dependent cndmask chain.
// ---------------------------------------------------------------------------
__global__ __launch_bounds__(256)
__attribute__((amdgpu_waves_per_eu(1, 1)))
void fps_kernel(const float* __restrict__ xyz, int* __restrict__ idx_out) {
  __shared__ float lx[N_], ly[N_], lz[N_];
  __shared__ unsigned long long slotbuf[2][4];
  __shared__ int idxl[S_];
  const int b = blockIdx.x;
  const int t = threadIdx.x;
  const float* base = xyz + (size_t)b * N_ * 3;
  // stage xyz (interleaved) -> SoA in LDS, coalesced float4 reads
  #pragma unroll
  for (int k = 0; k < 24; ++k) {
    int j = k * 256 + t;                        // float4 index
    float4 v = ((const float4*)base)[j];
    int f = j * 4;
    float vals[4] = {v.x, v.y, v.z, v.w};
    #pragma unroll
    for (int e = 0; e < 4; ++e) {
      int ff = f + e;
      int p = ff / 3;
      int c = ff - p * 3;
      if (c == 0) lx[p] = vals[e];
      else if (c == 1) ly[p] = vals[e];
      else lz[p] = vals[e];
    }
  }
  __syncthreads();
  const int p0 = t * 32;                         // contiguous points per thread
  float px[32], py[32], pz[32], dist[32];
  #pragma unroll
  for (int j = 0; j < 32; ++j) {
    px[j] = lx[p0 + j];
    py[j] = ly[p0 + j];
    pz[j] = lz[p0 + j];
    dist[j] = 1e10f;
  }
  // keep coords register-resident (no remat back to LDS reads)
  #pragma unroll
  for (int j = 0; j < 32; ++j)
    asm volatile("" : "+v"(px[j]), "+v"(py[j]), "+v"(pz[j]));

  int bidx = 0;
  float cx = lx[0], cy = ly[0], cz = lz[0];
  const int w = t >> 6;
  const bool is63 = ((t & 63) == 63);

  for (int s = 0; s < S_; ++s) {
    const int par = s & 1;
    if (t == 0) idxl[s] = bidx;                  // emit pre-update farthest
    float bestv = -1.0f;
    #pragma unroll
    for (int j = 0; j < 32; ++j) {
      float dx = __fsub_rn(px[j], cx);
      float dy = __fsub_rn(py[j], cy);
      float dz = __fsub_rn(pz[j], cz);
      float d = __fadd_rn(__fadd_rn(__fmul_rn(dx, dx), __fmul_rn(dy, dy)),
                          __fmul_rn(dz, dz));
      d = fminf(dist[j], d);
      dist[j] = d;
      bestv = fmaxf(bestv, d);                   // value-only, short chain
    }
    // lowest j with dist[j] == bestv (first occurrence), via min-tree
    unsigned keys[32];
    #pragma unroll
    for (int j = 0; j < 32; ++j)
      keys[j] = (dist[j] == bestv) ? (unsigned)j : 0xFFFFu;
    #pragma unroll
    for (int off = 16; off >= 1; off >>= 1)
      #pragma unroll
      for (int j = 0; j < off; ++j)
        keys[j] = keys[j] < keys[j + off] ? keys[j] : keys[j + off];
    int besti = p0 + (int)keys[0];
    // wave (64-lane) argmax via DPP: key = (dist_bits, 8191 - idx), lex max.
    // dist >= 0 so the fp32 bit pattern is order-preserving; DPP zero-fill
    // (val=0.0, nidx=0 -> idx 8191) can never beat a real key incorrectly.
    unsigned hi = __float_as_uint(bestv < 0.0f ? 0.0f : bestv);
    unsigned lo = (unsigned)(8191 - besti);
    DPP_MAX_STEP(0x111)   // row_shr:1
    DPP_MAX_STEP(0x112)   // row_shr:2
    DPP_MAX_STEP(0x114)   // row_shr:4
    DPP_MAX_STEP(0x118)   // row_shr:8
    DPP_MAX_STEP(0x142)   // row_bcast15
    DPP_MAX_STEP(0x143)   // row_bcast31  -> lane 63 has wave max
    if (is63) slotbuf[par][w] = ((unsigned long long)hi << 32) | lo;
    __syncthreads();
    // every thread redundantly combines the 4 wave keys (broadcast LDS reads)
    unsigned long long best = slotbuf[par][0];
    #pragma unroll
    for (int w2 = 1; w2 < 4; ++w2) {
      unsigned long long k2 = slotbuf[par][w2];
      if (k2 > best) best = k2;       // u64 >: val desc, then lowest idx
    }
    bidx = 8191 - (int)(unsigned)(best & 0xFFFFFFFFull);
    cx = lx[bidx]; cy = ly[bidx]; cz = lz[bidx];
    // next iteration writes slotbuf[par^1] -> one barrier per step is safe
  }
  for (int i = t; i < S_; i += 256) idx_out[b * S_ + i] = idxl[i];
}

// ---------------------------------------------------------------------------
// Kernel 2: gather + conv1(BN,ReLU) + conv2(BN) + proj. One block = 64 points
// of one batch. 256 threads as 8 (point groups) x 32 (output groups); each
// thread computes an 8x4 register tile. Weights staged transposed in LDS.
// Writes h2 (post-BN2) to ws, per-block column sums for the SE mean, and
// proj into d_out (used as scratch).
// ---------------------------------------------------------------------------
__global__ __launch_bounds__(256) void mlp_kernel(
    const float* __restrict__ xyz, const float* __restrict__ feat,
    const float* __restrict__ W1, const float* __restrict__ g1,
    const float* __restrict__ b1, const float* __restrict__ m1,
    const float* __restrict__ v1, const float* __restrict__ W2,
    const float* __restrict__ g2, const float* __restrict__ b2,
    const float* __restrict__ m2, const float* __restrict__ v2,
    const float* __restrict__ Wproj, const int* __restrict__ idx,
    float* __restrict__ h2buf, float* __restrict__ partials,
    float* __restrict__ projbuf) {
  __shared__ float xs[CIN][64];      // x tile, K-major
  __shared__ float hs[COUT][64];     // h1 tile, K-major
  __shared__ float wlds[COUT][COUT]; // current weight, [k][o]
  __shared__ float psums[8][COUT];
  const int blk = blockIdx.x;
  const int b = blk >> 3, tile = blk & 7;
  const int t = threadIdx.x;

  // gather 64 points: 4 threads per point
  {
    const int p = t >> 2, q = t & 3;
    const int pid = idx[b * S_ + tile * 64 + p];
    const float* frow = feat + ((size_t)(b * N_ + pid)) * C_ + q * 16;
    #pragma unroll
    for (int i = 0; i < 4; ++i) {
      float4 v = ((const float4*)frow)[i];
      xs[3 + q * 16 + i * 4 + 0][p] = v.x;
      xs[3 + q * 16 + i * 4 + 1][p] = v.y;
      xs[3 + q * 16 + i * 4 + 2][p] = v.z;
      xs[3 + q * 16 + i * 4 + 3][p] = v.w;
    }
    if (q == 0) {
      const float* xr = xyz + ((size_t)(b * N_ + pid)) * 3;
      xs[0][p] = xr[0]; xs[1][p] = xr[1]; xs[2][p] = xr[2];
    }
  }
  // stage W1 transposed: wlds[k][o] = W1[o*67+k]
  for (int f = t; f < COUT * CIN; f += 256) {
    int o = f / CIN, k = f - o * CIN;
    wlds[k][o] = W1[f];
  }
  __syncthreads();

  const int py = t >> 5, ox = t & 31;
  const int py8 = py * 8, ox4 = ox * 4;
  float acc[8][4];

  // ---- layer 1: h1 = relu(bn1(W1 @ x)) ----
  #pragma unroll
  for (int i = 0; i < 8; ++i)
    #pragma unroll
    for (int j = 0; j < 4; ++j) acc[i][j] = 0.0f;
  for (int k = 0; k < CIN; ++k) {
    float4 xa = *(const float4*)&xs[k][py8];
    float4 xb = *(const float4*)&xs[k][py8 + 4];
    float4 wv = *(const float4*)&wlds[k][ox4];
    float xv[8] = {xa.x, xa.y, xa.z, xa.w, xb.x, xb.y, xb.z, xb.w};
    float wr[4] = {wv.x, wv.y, wv.z, wv.w};
    #pragma unroll
    for (int i = 0; i < 8; ++i)
      #pragma unroll
      for (int j = 0; j < 4; ++j) acc[i][j] = fmaf(xv[i], wr[j], acc[i][j]);
  }
  #pragma unroll
  for (int j = 0; j < 4; ++j) {
    const int o = ox4 + j;
    const float sc = g1[o] * (1.0f / sqrtf(v1[o] + 1e-3f));
    const float sh = b1[o] - m1[o] * sc;
    #pragma unroll
    for (int i = 0; i < 8; ++i)
      hs[o][py8 + i] = fmaxf(fmaf(acc[i][j], sc, sh), 0.0f);
  }
  __syncthreads();                    // hs done, wlds free
  // stage W2: wlds[k][o] = W2[o*128+k]
  for (int f = t; f < COUT * COUT; f += 256) {
    int o = f >> 7, k = f & 127;
    wlds[k][o] = W2[f];
  }
  __syncthreads();

  // ---- layer 2: h2 = bn2(W2 @ h1) ----
  #pragma unroll
  for (int i = 0; i < 8; ++i)
    #pragma unroll
    for (int j = 0; j < 4; ++j) acc[i][j] = 0.0f;
  for (int k = 0; k < COUT; ++k) {
    float4 xa = *(const float4*)&hs[k][py8];
    float4 xb = *(const float4*)&hs[k][py8 + 4];
    float4 wv = *(const float4*)&wlds[k][ox4];
    float xv[8] = {xa.x, xa.y, xa.z, xa.w, xb.x, xb.y, xb.z, xb.w};
    float wr[4] = {wv.x, wv.y, wv.z, wv.w};
    #pragma unroll
    for (int i = 0; i < 8; ++i)
      #pragma unroll
      for (int j = 0; j < 4; ++j) acc[i][j] = fmaf(xv[i], wr[j], acc[i][j]);
  }
  {
    float sc[4], sh[4], sume[4];
    #pragma unroll
    for (int j = 0; j < 4; ++j) {
      const int o = ox4 + j;
      sc[j] = g2[o] * (1.0f / sqrtf(v2[o] + 1e-3f));
      sh[j] = b2[o] - m2[o] * sc[j];
      sume[j] = 0.0f;
    }
    const int basept = b * S_ + tile * 64 + py8;
    #pragma unroll
    for (int i = 0; i < 8; ++i) {
      float4 hv;
      hv.x = fmaf(acc[i][0], sc[0], sh[0]);
      hv.y = fmaf(acc[i][1], sc[1], sh[1]);
      hv.z = fmaf(acc[i][2], sc[2], sh[2]);
      hv.w = fmaf(acc[i][3], sc[3], sh[3]);
      sume[0] += hv.x; sume[1] += hv.y; sume[2] += hv.z; sume[3] += hv.w;
      *(float4*)&h2buf[((size_t)(basept + i)) * COUT + ox4] = hv;
    }
    *(float4*)&psums[py][ox4] = make_float4(sume[0], sume[1], sume[2], sume[3]);
  }
  __syncthreads();                    // psums done, wlds free
  if (t < COUT) {
    float sacc = 0.0f;
    #pragma unroll
    for (int r = 0; r < 8; ++r) sacc += psums[r][t];
    partials[(b * 8 + tile) * COUT + t] = sacc;
  }
  // stage Wproj
  for (int f = t; f < COUT * CIN; f += 256) {
    int o = f / CIN, k = f - o * CIN;
    wlds[k][o] = Wproj[f];
  }
  __syncthreads();

  // ---- proj = Wproj @ x ----
  #pragma unroll
  for (int i = 0; i < 8; ++i)
    #pragma unroll
    for (int j = 0; j < 4; ++j) acc[i][j] = 0.0f;
  for (int k = 0; k < CIN; ++k) {
    float4 xa = *(const float4*)&xs[k][py8];
    float4 xb = *(const float4*)&xs[k][py8 + 4];
    float4 wv = *(const float4*)&wlds[k][ox4];
    float xv[8] = {xa.x, xa.y, xa.z, xa.w, xb.x, xb.y, xb.z, xb.w};
    float wr[4] = {wv.x, wv.y, wv.z, wv.w};
    #pragma unroll
    for (int i = 0; i < 8; ++i)
      #pragma unroll
      for (int j = 0; j < 4; ++j) acc[i][j] = fmaf(xv[i], wr[j], acc[i][j]);
  }
  {
    const int basept = b * S_ + tile * 64 + py8;
    #pragma unroll
    for (int i = 0; i < 8; ++i) {
      float4 pv = make_float4(acc[i][0], acc[i][1], acc[i][2], acc[i][3]);
      *(float4*)&projbuf[((size_t)(basept + i)) * COUT + ox4] = pv;
    }
  }
}

// ---------------------------------------------------------------------------
// Kernel 3: SE gate. One block per batch, 128 threads.
// ---------------------------------------------------------------------------
__global__ __launch_bounds__(128) void se_kernel(
    const float* __restrict__ partials, const float* __restrict__ Wse1,
    const float* __restrict__ bse1, const float* __restrict__ Wse2,
    const float* __restrict__ bse2, float* __restrict__ sgate) {
  __shared__ float mv[COUT];
  __shared__ float rv[8];
  const int b = blockIdx.x;
  const int t = threadIdx.x;
  float s = 0.0f;
  #pragma unroll
  for (int r = 0; r < 8; ++r) s += partials[(b * 8 + r) * COUT + t];
  mv[t] = s * (1.0f / (float)S_);
  __syncthreads();
  if (t < 8) {
    float a = bse1[t];
    for (int o = 0; o < COUT; ++o) a = fmaf(mv[o], Wse1[t * COUT + o], a);
    rv[t] = fmaxf(a, 0.0f);
  }
  __syncthreads();
  float a = bse2[t];
  #pragma unroll
  for (int h = 0; h < 8; ++h) a = fmaf(rv[h], Wse2[t * 8 + h], a);
  sgate[b * COUT + t] = 1.0f / (1.0f + expf(-a));
}

// ---------------------------------------------------------------------------
// Kernel 4: out = relu(h2 * gate + proj), proj already resident in d_out.
// ---------------------------------------------------------------------------
__global__ __launch_bounds__(256) void finish_kernel(
    const float* __restrict__ h2buf, const float* __restrict__ sgate,
    float* __restrict__ out) {
  const int i = blockIdx.x * 256 + threadIdx.x;          // float4 index
  const int total = B_ * S_ * COUT / 4;                   // 524288
  if (i >= total) return;
  const int fo = i & 31;          // float4-within-row (128 floats = 32 f4)
  const int row = i >> 5;         // b*512 + s
  const int b = row >> 9;
  float4 h = ((const float4*)h2buf)[i];
  float4 g = ((const float4*)sgate)[b * 32 + fo];
  float4 p = ((float4*)out)[i];
  float4 r;
  r.x = fmaxf(fmaf(h.x, g.x, p.x), 0.0f);
  r.y = fmaxf(fmaf(h.y, g.y, p.y), 0.0f);
  r.z = fmaxf(fmaf(h.z, g.z, p.z), 0.0f);
  r.w = fmaxf(fmaf(h.w, g.w, p.w), 0.0f);
  ((float4*)out)[i] = r;
}

extern "C" void kernel_launch(void* const* d_in, const int* in_sizes, int n_in,
                              void* d_out, int out_size, void* d_ws, size_t ws_size,
                              hipStream_t stream) {
  const float* xyz   = (const float*)d_in[0];
  const float* feat  = (const float*)d_in[1];
  const float* W1    = (const float*)d_in[2];
  const float* g1    = (const float*)d_in[3];
  const float* b1    = (const float*)d_in[4];
  const float* m1    = (const float*)d_in[5];
  const float* v1    = (const float*)d_in[6];
  const float* W2    = (const float*)d_in[7];
  const float* g2    = (const float*)d_in[8];
  const float* b2    = (const float*)d_in[9];
  const float* m2    = (const float*)d_in[10];
  const float* v2    = (const float*)d_in[11];
  const float* Wproj = (const float*)d_in[12];
  const float* Wse1  = (const float*)d_in[13];
  const float* bse1  = (const float*)d_in[14];
  const float* Wse2  = (const float*)d_in[15];
  const float* bse2  = (const float*)d_in[16];
  float* out = (float*)d_out;

  char* ws = (char*)d_ws;
  int*   idx      = (int*)ws;                                   // 64 KB
  float* h2buf    = (float*)(ws + (64 << 10));                  // 8 MB
  float* partials = (float*)(ws + (64 << 10) + B_ * S_ * COUT * 4); // 128 KB
  float* sgate    = (float*)(ws + (64 << 10) + B_ * S_ * COUT * 4 +
                             B_ * 8 * COUT * 4);                // 16 KB

  fps_kernel<<<B_, 256, 0, stream>>>(xyz, idx);
  mlp_kernel<<<B_ * 8, 256, 0, stream>>>(xyz, feat, W1, g1, b1, m1, v1,
                                         W2, g2, b2, m2, v2, Wproj, idx,
                                         h2buf, partials, out);
  se_kernel<<<B_, 128, 0, stream>>>(partials, Wse1, bse1, Wse2, bse2, sgate);
  finish_kernel<<<(B_ * S_ * COUT / 4 + 255) / 256, 256, 0, stream>>>(h2buf, sgate, out);
}

// Round 9
// 524.696 us; speedup vs baseline: 1.1166x; 1.1166x over previous
//
#include <hip/hip_runtime.h>
#include <math.h>

#define B_ 32
#define N_ 8192
#define C_ 64
#define S_ 512
#define CIN 67
#define COUT 128

// ---------------------------------------------------------------------------
// DPP move helper: returns src shifted per CTRL; out-of-range lanes read 0.
// ---------------------------------------------------------------------------
template <int CTRL>
__device__ __forceinline__ unsigned dppmov(unsigned v) {
  return (unsigned)__builtin_amdgcn_update_dpp(0, (int)v, CTRL, 0xF, 0xF, true);
}
template <int CTRL>
__device__ __forceinline__ float dppmaxf(float v) {
  return fmaxf(v, __uint_as_float(dppmov<CTRL>(__float_as_uint(v))));
}

// ---------------------------------------------------------------------------
// Kernel 1: farthest point sampling. One block per batch, 256 threads
// (4 waves = 1 wave/SIMD), 32 points per thread; xyz mirrored in LDS (SoA).
// SCALAR __f*_rn distance math only (packed fp32 diverged twice: banned).
// vs r4 (both changes exact-semantics-preserving):
//  * argmax tracked in 4 independent groups of 8 (strict > within group =
//    first occurrence; ascending-group combine with strict > = global first
//    occurrence) -> serial cndmask chains 32-deep -> 8-deep.
//  * wave reduce: float DPP max (6 levels) -> M = readlane 63; winner lane
//    = lowest set bit of ballot(bestv==M) (lanes ascend in point order ->
//    lowest lane = lowest index, numpy tie-break preserved); besti fetched
//    with readlane. Cross-wave u64 slot scan unchanged (proven r4).
// ---------------------------------------------------------------------------
__global__ __launch_bounds__(256)
void fps_kernel(const float* __restrict__ xyz, int* __restrict__ idx_out) {
  __shared__ float lx[N_], ly[N_], lz[N_];
  __shared__ unsigned long long slotbuf[2][4];
  __shared__ int idxl[S_];
  const int b = blockIdx.x;
  const int t = threadIdx.x;
  const float* base = xyz + (size_t)b * N_ * 3;
  // stage xyz (interleaved) -> SoA in LDS, coalesced float4 reads
  #pragma unroll
  for (int k = 0; k < 24; ++k) {
    int j = k * 256 + t;                        // float4 index
    float4 v = ((const float4*)base)[j];
    int f = j * 4;
    float vals[4] = {v.x, v.y, v.z, v.w};
    #pragma unroll
    for (int e = 0; e < 4; ++e) {
      int ff = f + e;
      int p = ff / 3;
      int c = ff - p * 3;
      if (c == 0) lx[p] = vals[e];
      else if (c == 1) ly[p] = vals[e];
      else lz[p] = vals[e];
    }
  }
  __syncthreads();
  const int p0 = t * 32;                         // contiguous points per thread
  float px[32], py[32], pz[32], dist[32];
  #pragma unroll
  for (int j = 0; j < 32; ++j) {
    px[j] = lx[p0 + j];
    py[j] = ly[p0 + j];
    pz[j] = lz[p0 + j];
    dist[j] = 1e10f;
  }
  // keep coords register-resident (no remat back to LDS reads)
  #pragma unroll
  for (int j = 0; j < 32; ++j)
    asm volatile("" : "+v"(px[j]), "+v"(py[j]), "+v"(pz[j]));

  int bidx = 0;
  float cx = lx[0], cy = ly[0], cz = lz[0];
  const int w = t >> 6;
  const int lane = t & 63;

  for (int s = 0; s < S_; ++s) {
    const int par = s & 1;
    if (t == 0) idxl[s] = bidx;                  // emit pre-update farthest
    // --- update + 4-group argmax (8-deep serial chains, exact semantics) ---
    float gv[4];
    int gi[4];
    #pragma unroll
    for (int g = 0; g < 4; ++g) {
      gv[g] = -1.0f;
      gi[g] = 0;
      #pragma unroll
      for (int u = 0; u < 8; ++u) {
        const int j = g * 8 + u;
        float dx = __fsub_rn(px[j], cx);
        float dy = __fsub_rn(py[j], cy);
        float dz = __fsub_rn(pz[j], cz);
        float d = __fadd_rn(__fadd_rn(__fmul_rn(dx, dx), __fmul_rn(dy, dy)),
                            __fmul_rn(dz, dz));
        d = fminf(dist[j], d);
        dist[j] = d;
        if (d > gv[g]) { gv[g] = d; gi[g] = j; }   // strict > : first occurrence
      }
    }
    float bestv = gv[0];
    int bj = gi[0];
    #pragma unroll
    for (int g = 1; g < 4; ++g)
      if (gv[g] > bestv) { bestv = gv[g]; bj = gi[g]; }  // ascending: first occ.
    // --- wave max via float DPP (bestv >= 0, zero-fill safe) ---
    float m = bestv;
    m = dppmaxf<0x111>(m);   // row_shr:1
    m = dppmaxf<0x112>(m);   // row_shr:2
    m = dppmaxf<0x114>(m);   // row_shr:4
    m = dppmaxf<0x118>(m);   // row_shr:8
    m = dppmaxf<0x142>(m);   // row_bcast15
    m = dppmaxf<0x143>(m);   // row_bcast31 -> lane 63 holds wave max
    const float M = __uint_as_float(
        (unsigned)__builtin_amdgcn_readlane((int)__float_as_uint(m), 63));
    const unsigned long long ball = __ballot(bestv == M);
    const int l0 = __ffsll(ball) - 1;            // lowest lane = lowest index
    const int bj0 = __builtin_amdgcn_readlane(bj, l0);
    const int widx = ((w << 6) | l0) * 32 + bj0; // global point index of wave max
    if (lane == 63)
      slotbuf[par][w] =
          ((unsigned long long)__float_as_uint(M) << 32) | (unsigned)(8191 - widx);
    __syncthreads();
    // every thread redundantly combines the 4 wave keys (broadcast LDS reads)
    unsigned long long best = slotbuf[par][0];
    #pragma unroll
    for (int w2 = 1; w2 < 4; ++w2) {
      unsigned long long k2 = slotbuf[par][w2];
      if (k2 > best) best = k2;       // u64 >: val desc, then lowest idx
    }
    bidx = 8191 - (int)(unsigned)(best & 0xFFFFFFFFull);
    cx = lx[bidx]; cy = ly[bidx]; cz = lz[bidx];
    // next iteration writes slotbuf[par^1] -> one barrier per step is safe
  }
  for (int i = t; i < S_; i += 256) idx_out[b * S_ + i] = idxl[i];
}

// ---------------------------------------------------------------------------
// Kernel 2: gather + conv1(BN,ReLU) + conv2(BN) + proj. One block = 64 points
// of one batch. 256 threads as 8 (point groups) x 32 (output groups); each
// thread computes an 8x4 register tile. Weights staged transposed in LDS.
// Writes h2 (post-BN2) to ws, per-block column sums for the SE mean, and
// proj into d_out (used as scratch).
// ---------------------------------------------------------------------------
__global__ __launch_bounds__(256) void mlp_kernel(
    const float* __restrict__ xyz, const float* __restrict__ feat,
    const float* __restrict__ W1, const float* __restrict__ g1,
    const float* __restrict__ b1, const float* __restrict__ m1,
    const float* __restrict__ v1, const float* __restrict__ W2,
    const float* __restrict__ g2, const float* __restrict__ b2,
    const float* __restrict__ m2, const float* __restrict__ v2,
    const float* __restrict__ Wproj, const int* __restrict__ idx,
    float* __restrict__ h2buf, float* __restrict__ partials,
    float* __restrict__ projbuf) {
  __shared__ float xs[CIN][64];      // x tile, K-major
  __shared__ float hs[COUT][64];     // h1 tile, K-major
  __shared__ float wlds[COUT][COUT]; // current weight, [k][o]
  __shared__ float psums[8][COUT];
  const int blk = blockIdx.x;
  const int b = blk >> 3, tile = blk & 7;
  const int t = threadIdx.x;

  // gather 64 points: 4 threads per point
  {
    const int p = t >> 2, q = t & 3;
    const int pid = idx[b * S_ + tile * 64 + p];
    const float* frow = feat + ((size_t)(b * N_ + pid)) * C_ + q * 16;
    #pragma unroll
    for (int i = 0; i < 4; ++i) {
      float4 v = ((const float4*)frow)[i];
      xs[3 + q * 16 + i * 4 + 0][p] = v.x;
      xs[3 + q * 16 + i * 4 + 1][p] = v.y;
      xs[3 + q * 16 + i * 4 + 2][p] = v.z;
      xs[3 + q * 16 + i * 4 + 3][p] = v.w;
    }
    if (q == 0) {
      const float* xr = xyz + ((size_t)(b * N_ + pid)) * 3;
      xs[0][p] = xr[0]; xs[1][p] = xr[1]; xs[2][p] = xr[2];
    }
  }
  // stage W1 transposed: wlds[k][o] = W1[o*67+k]
  for (int f = t; f < COUT * CIN; f += 256) {
    int o = f / CIN, k = f - o * CIN;
    wlds[k][o] = W1[f];
  }
  __syncthreads();

  const int py = t >> 5, ox = t & 31;
  const int py8 = py * 8, ox4 = ox * 4;
  float acc[8][4];

  // ---- layer 1: h1 = relu(bn1(W1 @ x)) ----
  #pragma unroll
  for (int i = 0; i < 8; ++i)
    #pragma unroll
    for (int j = 0; j < 4; ++j) acc[i][j] = 0.0f;
  for (int k = 0; k < CIN; ++k) {
    float4 xa = *(const float4*)&xs[k][py8];
    float4 xb = *(const float4*)&xs[k][py8 + 4];
    float4 wv = *(const float4*)&wlds[k][ox4];
    float xv[8] = {xa.x, xa.y, xa.z, xa.w, xb.x, xb.y, xb.z, xb.w};
    float wr[4] = {wv.x, wv.y, wv.z, wv.w};
    #pragma unroll
    for (int i = 0; i < 8; ++i)
      #pragma unroll
      for (int j = 0; j < 4; ++j) acc[i][j] = fmaf(xv[i], wr[j], acc[i][j]);
  }
  #pragma unroll
  for (int j = 0; j < 4; ++j) {
    const int o = ox4 + j;
    const float sc = g1[o] * (1.0f / sqrtf(v1[o] + 1e-3f));
    const float sh = b1[o] - m1[o] * sc;
    #pragma unroll
    for (int i = 0; i < 8; ++i)
      hs[o][py8 + i] = fmaxf(fmaf(acc[i][j], sc, sh), 0.0f);
  }
  __syncthreads();                    // hs done, wlds free
  // stage W2: wlds[k][o] = W2[o*128+k]
  for (int f = t; f < COUT * COUT; f += 256) {
    int o = f >> 7, k = f & 127;
    wlds[k][o] = W2[f];
  }
  __syncthreads();

  // ---- layer 2: h2 = bn2(W2 @ h1) ----
  #pragma unroll
  for (int i = 0; i < 8; ++i)
    #pragma unroll
    for (int j = 0; j < 4; ++j) acc[i][j] = 0.0f;
  for (int k = 0; k < COUT; ++k) {
    float4 xa = *(const float4*)&hs[k][py8];
    float4 xb = *(const float4*)&hs[k][py8 + 4];
    float4 wv = *(const float4*)&wlds[k][ox4];
    float xv[8] = {xa.x, xa.y, xa.z, xa.w, xb.x, xb.y, xb.z, xb.w};
    float wr[4] = {wv.x, wv.y, wv.z, wv.w};
    #pragma unroll
    for (int i = 0; i < 8; ++i)
      #pragma unroll
      for (int j = 0; j < 4; ++j) acc[i][j] = fmaf(xv[i], wr[j], acc[i][j]);
  }
  {
    float sc[4], sh[4], sume[4];
    #pragma unroll
    for (int j = 0; j < 4; ++j) {
      const int o = ox4 + j;
      sc[j] = g2[o] * (1.0f / sqrtf(v2[o] + 1e-3f));
      sh[j] = b2[o] - m2[o] * sc[j];
      sume[j] = 0.0f;
    }
    const int basept = b * S_ + tile * 64 + py8;
    #pragma unroll
    for (int i = 0; i < 8; ++i) {
      float4 hv;
      hv.x = fmaf(acc[i][0], sc[0], sh[0]);
      hv.y = fmaf(acc[i][1], sc[1], sh[1]);
      hv.z = fmaf(acc[i][2], sc[2], sh[2]);
      hv.w = fmaf(acc[i][3], sc[3], sh[3]);
      sume[0] += hv.x; sume[1] += hv.y; sume[2] += hv.z; sume[3] += hv.w;
      *(float4*)&h2buf[((size_t)(basept + i)) * COUT + ox4] = hv;
    }
    *(float4*)&psums[py][ox4] = make_float4(sume[0], sume[1], sume[2], sume[3]);
  }
  __syncthreads();                    // psums done, wlds free
  if (t < COUT) {
    float sacc = 0.0f;
    #pragma unroll
    for (int r = 0; r < 8; ++r) sacc += psums[r][t];
    partials[(b * 8 + tile) * COUT + t] = sacc;
  }
  // stage Wproj
  for (int f = t; f < COUT * CIN; f += 256) {
    int o = f / CIN, k = f - o * CIN;
    wlds[k][o] = Wproj[f];
  }
  __syncthreads();

  // ---- proj = Wproj @ x ----
  #pragma unroll
  for (int i = 0; i < 8; ++i)
    #pragma unroll
    for (int j = 0; j < 4; ++j) acc[i][j] = 0.0f;
  for (int k = 0; k < CIN; ++k) {
    float4 xa = *(const float4*)&xs[k][py8];
    float4 xb = *(const float4*)&xs[k][py8 + 4];
    float4 wv = *(const float4*)&wlds[k][ox4];
    float xv[8] = {xa.x, xa.y, xa.z, xa.w, xb.x, xb.y, xb.z, xb.w};
    float wr[4] = {wv.x, wv.y, wv.z, wv.w};
    #pragma unroll
    for (int i = 0; i < 8; ++i)
      #pragma unroll
      for (int j = 0; j < 4; ++j) acc[i][j] = fmaf(xv[i], wr[j], acc[i][j]);
  }
  {
    const int basept = b * S_ + tile * 64 + py8;
    #pragma unroll
    for (int i = 0; i < 8; ++i) {
      float4 pv = make_float4(acc[i][0], acc[i][1], acc[i][2], acc[i][3]);
      *(float4*)&projbuf[((size_t)(basept + i)) * COUT + ox4] = pv;
    }
  }
}

// ---------------------------------------------------------------------------
// Kernel 3: SE gate. One block per batch, 128 threads.
// ---------------------------------------------------------------------------
__global__ __launch_bounds__(128) void se_kernel(
    const float* __restrict__ partials, const float* __restrict__ Wse1,
    const float* __restrict__ bse1, const float* __restrict__ Wse2,
    const float* __restrict__ bse2, float* __restrict__ sgate) {
  __shared__ float mv[COUT];
  __shared__ float rv[8];
  const int b = blockIdx.x;
  const int t = threadIdx.x;
  float s = 0.0f;
  #pragma unroll
  for (int r = 0; r < 8; ++r) s += partials[(b * 8 + r) * COUT + t];
  mv[t] = s * (1.0f / (float)S_);
  __syncthreads();
  if (t < 8) {
    float a = bse1[t];
    for (int o = 0; o < COUT; ++o) a = fmaf(mv[o], Wse1[t * COUT + o], a);
    rv[t] = fmaxf(a, 0.0f);
  }
  __syncthreads();
  float a = bse2[t];
  #pragma unroll
  for (int h = 0; h < 8; ++h) a = fmaf(rv[h], Wse2[t * 8 + h], a);
  sgate[b * COUT + t] = 1.0f / (1.0f + expf(-a));
}

// ---------------------------------------------------------------------------
// Kernel 4: out = relu(h2 * gate + proj), proj already resident in d_out.
// ---------------------------------------------------------------------------
__global__ __launch_bounds__(256) void finish_kernel(
    const float* __restrict__ h2buf, const float* __restrict__ sgate,
    float* __restrict__ out) {
  const int i = blockIdx.x * 256 + threadIdx.x;          // float4 index
  const int total = B_ * S_ * COUT / 4;                   // 524288
  if (i >= total) return;
  const int fo = i & 31;          // float4-within-row (128 floats = 32 f4)
  const int row = i >> 5;         // b*512 + s
  const int b = row >> 9;
  float4 h = ((const float4*)h2buf)[i];
  float4 g = ((const float4*)sgate)[b * 32 + fo];
  float4 p = ((float4*)out)[i];
  float4 r;
  r.x = fmaxf(fmaf(h.x, g.x, p.x), 0.0f);
  r.y = fmaxf(fmaf(h.y, g.y, p.y), 0.0f);
  r.z = fmaxf(fmaf(h.z, g.z, p.z), 0.0f);
  r.w = fmaxf(fmaf(h.w, g.w, p.w), 0.0f);
  ((float4*)out)[i] = r;
}

extern "C" void kernel_launch(void* const* d_in, const int* in_sizes, int n_in,
                              void* d_out, int out_size, void* d_ws, size_t ws_size,
                              hipStream_t stream) {
  const float* xyz   = (const float*)d_in[0];
  const float* feat  = (const float*)d_in[1];
  const float* W1    = (const float*)d_in[2];
  const float* g1    = (const float*)d_in[3];
  const float* b1    = (const float*)d_in[4];
  const float* m1    = (const float*)d_in[5];
  const float* v1    = (const float*)d_in[6];
  const float* W2    = (const float*)d_in[7];
  const float* g2    = (const float*)d_in[8];
  const float* b2    = (const float*)d_in[9];
  const float* m2    = (const float*)d_in[10];
  const float* v2    = (const float*)d_in[11];
  const float* Wproj = (const float*)d_in[12];
  const float* Wse1  = (const float*)d_in[13];
  const float* bse1  = (const float*)d_in[14];
  const float* Wse2  = (const float*)d_in[15];
  const float* bse2  = (const float*)d_in[16];
  float* out = (float*)d_out;

  char* ws = (char*)d_ws;
  int*   idx      = (int*)ws;                                   // 64 KB
  float* h2buf    = (float*)(ws + (64 << 10));                  // 8 MB
  float* partials = (float*)(ws + (64 << 10) + B_ * S_ * COUT * 4); // 128 KB
  float* sgate    = (float*)(ws + (64 << 10) + B_ * S_ * COUT * 4 +
                             B_ * 8 * COUT * 4);                // 16 KB

  fps_kernel<<<B_, 256, 0, stream>>>(xyz, idx);
  mlp_kernel<<<B_ * 8, 256, 0, stream>>>(xyz, feat, W1, g1, b1, m1, v1,
                                         W2, g2, b2, m2, v2, Wproj, idx,
                                         h2buf, partials, out);
  se_kernel<<<B_, 128, 0, stream>>>(partials, Wse1, bse1, Wse2, bse2, sgate);
  finish_kernel<<<(B_ * S_ * COUT / 4 + 255) / 256, 256, 0, stream>>>(h2buf, sgate, out);
}